// Round 9
// baseline (27.483 us; speedup 1.0000x reference)
//
#include <hip/hip_runtime.h>

// LengthRegulator fused single-kernel (R8 config, DIAGNOSTIC: dispatched
// twice back-to-back; second dispatch is idempotent). R9 - R8 estimates
// kernel+dispatch cost, separating graph-fixed overhead from kernel time.
//
// reps = floor(dur + 0.5); out[b, m, :] = inputs[b, t, :] where
// cumsum[b][t] <= m < cumsum[b][t+1]; zeros for m >= output_lens[b].
// d_out = out flat [B*max_len*D] ++ output_lens [B] (as float).

#define BATCH 16
#define T_IN 512
#define DIM 384
#define D4 96            // float4 per row
#define FPB 24           // output frames per block
#define VPB (FPB * D4)   // 2304 float4 vectors per block
#define NT 256           // threads per block (4 waves)

typedef float floatx4 __attribute__((ext_vector_type(4)));

__global__ __launch_bounds__(NT) void lr_fused_kernel(
    const float* __restrict__ dur,
    const floatx4* __restrict__ in4,
    floatx4* __restrict__ out4,
    float* __restrict__ lens_out,
    int max_len, int gx) {
    __shared__ int wsum[NT / 64];
    __shared__ int smap[FPB];

    // XCD-chunked swizzle.
    const int nwg = gridDim.x;               // 16 * gx, divisible by 8
    const int id = blockIdx.x;
    const int wid = (id & 7) * (nwg >> 3) + (id >> 3);
    const int b = wid / gx;                  // batch
    const int fx = wid - b * gx;             // frame-chunk within batch

    const int tid = threadIdx.x;
    const int lane = tid & 63;
    const int w = tid >> 6;

    // ---- scan: 512 reps, 2 per thread, registers only ----
    float2 dp = *(const float2*)(dur + b * T_IN + 2 * tid);
    int r0 = (int)floorf(dp.x + 0.5f);
    int r1 = (int)floorf(dp.y + 0.5f);
    int s = r0 + r1;
    int incl = s;
    #pragma unroll
    for (int off = 1; off < 64; off <<= 1) {
        int v = __shfl_up(incl, off);
        if (lane >= off) incl += v;
    }
    if (lane == 63) wsum[w] = incl;
    if (tid < FPB) smap[tid] = -1;   // default: zero-fill frame
    __syncthreads();

    int waveoff = 0;
    #pragma unroll
    for (int i = 0; i < NT / 64; ++i)
        if (i < w) waveoff += wsum[i];

    const int c0 = waveoff + incl - s;  // cumsum before token 2*tid
    const int c1 = c0 + r0;             // before token 2*tid+1
    const int c2 = c0 + s;              // before token 2*tid+2

    const int f0 = fx * FPB;
    const int f1 = f0 + FPB;
    {
        int lo = max(c0, f0), hi = min(c1, f1);
        for (int j = lo; j < hi; ++j) smap[j - f0] = 2 * tid;
        lo = max(c1, f0); hi = min(c2, f1);
        for (int j = lo; j < hi; ++j) smap[j - f0] = 2 * tid + 1;
    }
    if (fx == 0 && tid == NT - 1) lens_out[b] = (float)c2;
    __syncthreads();

    // ---- gather: 24 frames = 2304 float4, 9 per thread ----
    const int per_b = max_len * D4;
    const int v0 = fx * VPB;
    const floatx4* src_b = in4 + (size_t)b * T_IN * D4;
    floatx4* dst_b = out4 + (size_t)b * per_b;

    #pragma unroll
    for (int k = 0; k < VPB / NT; ++k) {
        int lv = tid + k * NT;          // 0..2303 within block chunk
        int v = v0 + lv;
        if (v >= per_b) break;          // padded chunks exit here
        int ml = lv / D4;               // local frame 0..23 (const divisor)
        int d4 = lv - ml * D4;
        int t = smap[ml];
        floatx4 val = (floatx4)(0.f);
        if (t >= 0) val = src_b[t * D4 + d4];
        __builtin_nontemporal_store(val, &dst_b[v]);
    }
}

extern "C" void kernel_launch(void* const* d_in, const int* in_sizes, int n_in,
                              void* d_out, int out_size, void* d_ws, size_t ws_size,
                              hipStream_t stream) {
    const float* inputs = (const float*)d_in[0];
    const float* durations = (const float*)d_in[1];
    float* out = (float*)d_out;

    const int max_len = (out_size - BATCH) / (BATCH * DIM);
    float* lens_out = out + (size_t)BATCH * max_len * DIM;

    int gx = (max_len + FPB - 1) / FPB;
    gx = (gx + 15) & ~15;
    dim3 grid(gx * BATCH);
    // DIAGNOSTIC: two identical dispatches. dur(R9) - dur(R8) ~= kernel+launch.
    lr_fused_kernel<<<grid, NT, 0, stream>>>(durations, (const floatx4*)inputs,
                                             (floatx4*)out, lens_out, max_len,
                                             gx);
    lr_fused_kernel<<<grid, NT, 0, stream>>>(durations, (const floatx4*)inputs,
                                             (floatx4*)out, lens_out, max_len,
                                             gx);
}

// Round 10
// 16.278 us; speedup vs baseline: 1.6883x; 1.6883x over previous
//
#include <hip/hip_runtime.h>

// LengthRegulator fused single-kernel (best config, R8; diagnostic 2nd
// dispatch removed). Measured decomposition (R9-R8): kernel ~11 us,
// fixed graph/harness overhead ~5 us. WRITE_SIZE = 52.7 MB (minimal),
// FETCH_SIZE = 5.7 MB (L3-served) -> ~95% of mixed-stream roofline.
//
// reps = floor(dur + 0.5); out[b, m, :] = inputs[b, t, :] where
// cumsum[b][t] <= m < cumsum[b][t+1]; zeros for m >= output_lens[b].
// d_out = out flat [B*max_len*D] ++ output_lens [B] (as float).

#define BATCH 16
#define T_IN 512
#define DIM 384
#define D4 96            // float4 per row
#define FPB 24           // output frames per block
#define VPB (FPB * D4)   // 2304 float4 vectors per block
#define NT 256           // threads per block (4 waves)

typedef float floatx4 __attribute__((ext_vector_type(4)));

__global__ __launch_bounds__(NT) void lr_fused_kernel(
    const float* __restrict__ dur,
    const floatx4* __restrict__ in4,
    floatx4* __restrict__ out4,
    float* __restrict__ lens_out,
    int max_len, int gx) {
    __shared__ int wsum[NT / 64];
    __shared__ int smap[FPB];

    // XCD-chunked swizzle: give XCD k a contiguous range of frame chunks.
    const int nwg = gridDim.x;               // 16 * gx, divisible by 8
    const int id = blockIdx.x;
    const int wid = (id & 7) * (nwg >> 3) + (id >> 3);
    const int b = wid / gx;                  // batch
    const int fx = wid - b * gx;             // frame-chunk within batch

    const int tid = threadIdx.x;
    const int lane = tid & 63;
    const int w = tid >> 6;

    // ---- scan: 512 reps, 2 per thread, registers only ----
    float2 dp = *(const float2*)(dur + b * T_IN + 2 * tid);
    int r0 = (int)floorf(dp.x + 0.5f);
    int r1 = (int)floorf(dp.y + 0.5f);
    int s = r0 + r1;
    int incl = s;
    #pragma unroll
    for (int off = 1; off < 64; off <<= 1) {
        int v = __shfl_up(incl, off);
        if (lane >= off) incl += v;
    }
    if (lane == 63) wsum[w] = incl;
    if (tid < FPB) smap[tid] = -1;   // default: zero-fill frame
    __syncthreads();

    int waveoff = 0;
    #pragma unroll
    for (int i = 0; i < NT / 64; ++i)
        if (i < w) waveoff += wsum[i];

    const int c0 = waveoff + incl - s;  // cumsum before token 2*tid
    const int c1 = c0 + r0;             // before token 2*tid+1
    const int c2 = c0 + s;              // before token 2*tid+2

    const int f0 = fx * FPB;
    const int f1 = f0 + FPB;
    // scatter: token 2*tid covers frames [c0, c1), token 2*tid+1 [c1, c2)
    {
        int lo = max(c0, f0), hi = min(c1, f1);
        for (int j = lo; j < hi; ++j) smap[j - f0] = 2 * tid;
        lo = max(c1, f0); hi = min(c2, f1);
        for (int j = lo; j < hi; ++j) smap[j - f0] = 2 * tid + 1;
    }
    if (fx == 0 && tid == NT - 1) lens_out[b] = (float)c2;
    __syncthreads();

    // ---- gather: 24 frames = 2304 float4, 9 per thread ----
    const int per_b = max_len * D4;
    const int v0 = fx * VPB;
    const floatx4* src_b = in4 + (size_t)b * T_IN * D4;
    floatx4* dst_b = out4 + (size_t)b * per_b;

    #pragma unroll
    for (int k = 0; k < VPB / NT; ++k) {
        int lv = tid + k * NT;          // 0..2303 within block chunk
        int v = v0 + lv;
        if (v >= per_b) break;          // padded chunks exit here
        int ml = lv / D4;               // local frame 0..23 (const divisor)
        int d4 = lv - ml * D4;
        int t = smap[ml];
        floatx4 val = (floatx4)(0.f);
        if (t >= 0) val = src_b[t * D4 + d4];
        __builtin_nontemporal_store(val, &dst_b[v]);
    }
}

extern "C" void kernel_launch(void* const* d_in, const int* in_sizes, int n_in,
                              void* d_out, int out_size, void* d_ws, size_t ws_size,
                              hipStream_t stream) {
    const float* inputs = (const float*)d_in[0];
    const float* durations = (const float*)d_in[1];
    float* out = (float*)d_out;

    const int max_len = (out_size - BATCH) / (BATCH * DIM);
    float* lens_out = out + (size_t)BATCH * max_len * DIM;

    // Pad chunks/batch to a multiple of 16 -> total blocks multiple of 256.
    int gx = (max_len + FPB - 1) / FPB;
    gx = (gx + 15) & ~15;
    dim3 grid(gx * BATCH);
    lr_fused_kernel<<<grid, NT, 0, stream>>>(durations, (const floatx4*)inputs,
                                             (floatx4*)out, lens_out, max_len,
                                             gx);
}